// Round 2
// baseline (355.508 us; speedup 1.0000x reference)
//
#include <hip/hip_runtime.h>

typedef unsigned short u16;
typedef __bf16 bf16x8 __attribute__((ext_vector_type(8)));
typedef unsigned short u16x8 __attribute__((ext_vector_type(8)));
typedef float f32x4 __attribute__((ext_vector_type(4)));

#define GP 72  // LDS row pitch in bf16 elements (144B: 16B-aligned, conflict-light)

static __device__ __forceinline__ u16 f2b(float f) {
  union { float f; unsigned u; } x; x.f = f;
  unsigned r = x.u + 0x7FFFu + ((x.u >> 16) & 1u);  // RNE
  return (u16)(r >> 16);
}

static __device__ __forceinline__ bf16x8 ld_frag(const u16* p) {
  union { u16x8 s; bf16x8 b; } u;
  u.s = *reinterpret_cast<const u16x8*>(p);
  return u.b;
}

// ---------------- f32 -> bf16 convert (vectorized x4) ----------------
__global__ __launch_bounds__(256) void cvt_f32_bf16(const float* __restrict__ in,
                                                    u16* __restrict__ out, int n4) {
  int i = blockIdx.x * 256 + threadIdx.x;
  if (i >= n4) return;
  float4 v = reinterpret_cast<const float4*>(in)[i];
  ushort4 o;
  o.x = f2b(v.x); o.y = f2b(v.y); o.z = f2b(v.z); o.w = f2b(v.w);
  reinterpret_cast<ushort4*>(out)[i] = o;
}

// ---------------- GEMM: out[M,N] = (A[M,K] @ Bt[N,K]^T + bias) * scale ----------------
// 64x64 tile, BK=64, 4 waves (2x2), each wave 32x32 via 2x2 16x16x32 MFMA frags.
__global__ __launch_bounds__(256) void gemm_bt(
    const u16* __restrict__ A, const u16* __restrict__ Bt,
    const float* __restrict__ bias, void* __restrict__ outp,
    int M, int N, int K, float scale, int out_bf16) {
  __shared__ alignas(16) u16 As[64 * GP];
  __shared__ alignas(16) u16 Bs[64 * GP];
  const int tid = threadIdx.x;
  const int wid = tid >> 6, lane = tid & 63;
  const int wr = wid >> 1, wc = wid & 1;
  const int row0 = blockIdx.x * 64, col0 = blockIdx.y * 64;
  f32x4 acc[2][2] = {};
  const int r1 = tid >> 3;          // 0..31
  const int c1 = (tid & 7) * 8;     // 0..56 step 8

  for (int k0 = 0; k0 < K; k0 += 64) {
    __syncthreads();
    *reinterpret_cast<int4*>(&As[r1 * GP + c1]) =
        *reinterpret_cast<const int4*>(&A[(size_t)(row0 + r1) * K + k0 + c1]);
    *reinterpret_cast<int4*>(&As[(r1 + 32) * GP + c1]) =
        *reinterpret_cast<const int4*>(&A[(size_t)(row0 + r1 + 32) * K + k0 + c1]);
    *reinterpret_cast<int4*>(&Bs[r1 * GP + c1]) =
        *reinterpret_cast<const int4*>(&Bt[(size_t)(col0 + r1) * K + k0 + c1]);
    *reinterpret_cast<int4*>(&Bs[(r1 + 32) * GP + c1]) =
        *reinterpret_cast<const int4*>(&Bt[(size_t)(col0 + r1 + 32) * K + k0 + c1]);
    __syncthreads();
    const int frow = lane & 15, fk = (lane >> 4) * 8;
#pragma unroll
    for (int ks = 0; ks < 2; ++ks) {
      bf16x8 a0 = ld_frag(&As[(wr * 32 + frow) * GP + ks * 32 + fk]);
      bf16x8 a1 = ld_frag(&As[(wr * 32 + 16 + frow) * GP + ks * 32 + fk]);
      bf16x8 b0 = ld_frag(&Bs[(wc * 32 + frow) * GP + ks * 32 + fk]);
      bf16x8 b1 = ld_frag(&Bs[(wc * 32 + 16 + frow) * GP + ks * 32 + fk]);
      acc[0][0] = __builtin_amdgcn_mfma_f32_16x16x32_bf16(a0, b0, acc[0][0], 0, 0, 0);
      acc[0][1] = __builtin_amdgcn_mfma_f32_16x16x32_bf16(a0, b1, acc[0][1], 0, 0, 0);
      acc[1][0] = __builtin_amdgcn_mfma_f32_16x16x32_bf16(a1, b0, acc[1][0], 0, 0, 0);
      acc[1][1] = __builtin_amdgcn_mfma_f32_16x16x32_bf16(a1, b1, acc[1][1], 0, 0, 0);
    }
  }
  // epilogue: D layout col=lane&15, row=(lane>>4)*4+r  [verified m89/m91]
  const int col = lane & 15, rb = (lane >> 4) * 4;
#pragma unroll
  for (int m = 0; m < 2; ++m)
#pragma unroll
    for (int n = 0; n < 2; ++n) {
      const int gc = col0 + wc * 32 + n * 16 + col;
      const float bv = bias[gc];
#pragma unroll
      for (int r = 0; r < 4; ++r) {
        const int gr = row0 + wr * 32 + m * 16 + rb + r;
        const float v = (acc[m][n][r] + bv) * scale;
        if (out_bf16)
          reinterpret_cast<u16*>(outp)[(size_t)gr * N + gc] = f2b(v);
        else
          reinterpret_cast<float*>(outp)[(size_t)gr * N + gc] = v;
      }
    }
}

// ---------------- Flash attention with ALiBi + causal ----------------
// grid: (T/64, B*H). block: 256 (4 waves), wave w owns q rows [qBase+16w, +16).
__global__ __launch_bounds__(256) void attn_kernel(
    const u16* __restrict__ qb,   // [B*T, 1024] bf16, pre-scaled by 1/8
    const u16* __restrict__ kvb,  // [B*T, 2048] bf16 (k: cols h*64, v: 1024+h*64)
    u16* __restrict__ yb,         // [B*T, 1024] bf16
    int T) {
  const int C = 1024;
  const int qt = blockIdx.x;
  const int bh = blockIdx.y;
  const int b = bh >> 4, h = bh & 15;
  const float slope = (float)(h + 1) * 0.0625f;  // (h+1)/16
  const int tid = threadIdx.x, wid = tid >> 6, lane = tid & 63;
  const int qBase = qt * 64;

  __shared__ alignas(16) u16 Ks[64 * GP];
  __shared__ alignas(16) u16 Vs[64 * GP];
  __shared__ alignas(16) u16 Ps[4][16 * GP];

  const int frow = lane & 15, fk = (lane >> 4) * 8;
  const int col = lane & 15, rb = (lane >> 4) * 4;

  // Q fragments (loop-invariant): row = lane&15 within the wave's 16 rows
  const int q_row = qBase + wid * 16 + frow;
  const u16* qp = qb + (size_t)(b * T + q_row) * C + h * 64;
  const bf16x8 aq0 = ld_frag(qp + fk);
  const bf16x8 aq1 = ld_frag(qp + 32 + fk);

  float mrow[4] = {-1e30f, -1e30f, -1e30f, -1e30f};
  float lrow[4] = {0.f, 0.f, 0.f, 0.f};
  f32x4 accO[4] = {};

  const int sr = tid >> 3;        // 0..31
  const int sc = (tid & 7) * 8;   // 0..56

  for (int kt = 0; kt <= qt; ++kt) {
    const int kBase = kt * 64;
    __syncthreads();
    {  // stage K,V 64x64 tiles
      const size_t g0 = (size_t)(b * T + kBase + sr) * 2048 + h * 64 + sc;
      const size_t g1 = (size_t)(b * T + kBase + sr + 32) * 2048 + h * 64 + sc;
      *reinterpret_cast<int4*>(&Ks[sr * GP + sc]) = *reinterpret_cast<const int4*>(&kvb[g0]);
      *reinterpret_cast<int4*>(&Ks[(sr + 32) * GP + sc]) = *reinterpret_cast<const int4*>(&kvb[g1]);
      *reinterpret_cast<int4*>(&Vs[sr * GP + sc]) = *reinterpret_cast<const int4*>(&kvb[g0 + 1024]);
      *reinterpret_cast<int4*>(&Vs[(sr + 32) * GP + sc]) = *reinterpret_cast<const int4*>(&kvb[g1 + 1024]);
    }
    __syncthreads();

    // S = Q K^T (per wave: 16 q-rows x 64 keys)
    f32x4 accS[4] = {};
#pragma unroll
    for (int n = 0; n < 4; ++n) {
      bf16x8 bk0 = ld_frag(&Ks[(n * 16 + frow) * GP + fk]);
      accS[n] = __builtin_amdgcn_mfma_f32_16x16x32_bf16(aq0, bk0, accS[n], 0, 0, 0);
      bf16x8 bk1 = ld_frag(&Ks[(n * 16 + frow) * GP + 32 + fk]);
      accS[n] = __builtin_amdgcn_mfma_f32_16x16x32_bf16(aq1, bk1, accS[n], 0, 0, 0);
    }

    // online softmax per owned row r (rows replicated across each 16-lane group)
#pragma unroll
    for (int r = 0; r < 4; ++r) {
      const int qg = qBase + wid * 16 + rb + r;
      float s[4];
      float tmax = -1e30f;
#pragma unroll
      for (int n = 0; n < 4; ++n) {
        const int kg = kBase + n * 16 + col;
        float v = accS[n][r] + slope * (float)(kg - qg);
        if (kg > qg) v = -1e30f;
        s[n] = v;
        tmax = fmaxf(tmax, v);
      }
      tmax = fmaxf(tmax, __shfl_xor(tmax, 1));
      tmax = fmaxf(tmax, __shfl_xor(tmax, 2));
      tmax = fmaxf(tmax, __shfl_xor(tmax, 4));
      tmax = fmaxf(tmax, __shfl_xor(tmax, 8));
      const float newm = fmaxf(mrow[r], tmax);
      const float corr = __expf(mrow[r] - newm);
      mrow[r] = newm;
      float psum = 0.f;
#pragma unroll
      for (int n = 0; n < 4; ++n) {
        const float p = __expf(s[n] - newm);
        psum += p;
        Ps[wid][(rb + r) * GP + n * 16 + col] = f2b(p);
      }
      psum += __shfl_xor(psum, 1);
      psum += __shfl_xor(psum, 2);
      psum += __shfl_xor(psum, 4);
      psum += __shfl_xor(psum, 8);
      lrow[r] = lrow[r] * corr + psum;
#pragma unroll
      for (int n = 0; n < 4; ++n) accO[n][r] *= corr;
    }
    __syncthreads();  // P visible (and keeps waves lockstep before next stage)

    // O += P @ V
#pragma unroll
    for (int ks = 0; ks < 2; ++ks) {
      bf16x8 ap = ld_frag(&Ps[wid][frow * GP + ks * 32 + fk]);
#pragma unroll
      for (int n = 0; n < 4; ++n) {
        u16x8 bvv;
#pragma unroll
        for (int j = 0; j < 8; ++j)
          bvv[j] = Vs[(ks * 32 + fk + j) * GP + n * 16 + col];
        union { u16x8 s; bf16x8 b; } u; u.s = bvv;
        accO[n] = __builtin_amdgcn_mfma_f32_16x16x32_bf16(ap, u.b, accO[n], 0, 0, 0);
      }
    }
  }

  // normalize + store
#pragma unroll
  for (int r = 0; r < 4; ++r) {
    const float inv = 1.0f / lrow[r];
    const int qg = qBase + wid * 16 + rb + r;
    u16* yrow = yb + (size_t)(b * T + qg) * C + h * 64;
#pragma unroll
    for (int n = 0; n < 4; ++n) yrow[n * 16 + col] = f2b(accO[n][r] * inv);
  }
}

extern "C" void kernel_launch(void* const* d_in, const int* in_sizes, int n_in,
                              void* d_out, int out_size, void* d_ws, size_t ws_size,
                              hipStream_t stream) {
  const float* x   = (const float*)d_in[0];
  // d_in[1] = freqs_cis (unused under ALiBi)
  const float* Wq  = (const float*)d_in[2];
  const float* bq  = (const float*)d_in[3];
  const float* Wkv = (const float*)d_in[4];
  const float* bkv = (const float*)d_in[5];
  const float* Wo  = (const float*)d_in[6];
  const float* bo  = (const float*)d_in[7];
  float* out = (float*)d_out;

  const int B = 2, T = 2048, C = 1024;
  const int M = B * T;  // 4096

  char* ws = (char*)d_ws;
  u16* xb   = (u16*)(ws + 0);          // 4096x1024  (8 MiB)
  u16* wqb  = (u16*)(ws + 8388608);    // 1024x1024  (2 MiB)
  u16* wkvb = (u16*)(ws + 10485760);   // 2048x1024  (4 MiB)
  u16* wob  = (u16*)(ws + 14680064);   // 1024x1024  (2 MiB)
  u16* qb   = (u16*)(ws + 16777216);   // 4096x1024  (8 MiB)
  u16* kvb  = (u16*)(ws + 25165824);   // 4096x2048  (16 MiB)
  u16* yb   = (u16*)(ws + 41943040);   // 4096x1024  (8 MiB)

  cvt_f32_bf16<<<(M * C / 4 + 255) / 256, 256, 0, stream>>>(x, xb, M * C / 4);
  cvt_f32_bf16<<<(C * C / 4 + 255) / 256, 256, 0, stream>>>(Wq, wqb, C * C / 4);
  cvt_f32_bf16<<<(2 * C * C / 4 + 255) / 256, 256, 0, stream>>>(Wkv, wkvb, 2 * C * C / 4);
  cvt_f32_bf16<<<(C * C / 4 + 255) / 256, 256, 0, stream>>>(Wo, wob, C * C / 4);

  // q = (x @ Wq^T + bq) * 0.125   [fold 1/sqrt(64) into q]
  gemm_bt<<<dim3(M / 64, C / 64), 256, 0, stream>>>(xb, wqb, bq, qb, M, C, C, 0.125f, 1);
  // kv = x @ Wkv^T + bkv
  gemm_bt<<<dim3(M / 64, 2 * C / 64), 256, 0, stream>>>(xb, wkvb, bkv, kvb, M, 2 * C, C, 1.0f, 1);
  // flash attention
  attn_kernel<<<dim3(T / 64, B * 16), 256, 0, stream>>>(qb, kvb, yb, T);
  // out = y @ Wo^T + bo  (f32 out)
  gemm_bt<<<dim3(M / 64, C / 64), 256, 0, stream>>>(yb, wob, bo, out, M, C, C, 1.0f, 0);
}

// Round 3
// 238.188 us; speedup vs baseline: 1.4926x; 1.4926x over previous
//
#include <hip/hip_runtime.h>

typedef unsigned short u16;
typedef __bf16 bf16x8 __attribute__((ext_vector_type(8)));
typedef unsigned short u16x8 __attribute__((ext_vector_type(8)));
typedef float f32x4 __attribute__((ext_vector_type(4)));

#define GP 72  // LDS row pitch in bf16 elements (144B: 16B-aligned, slot-spread)
#define KEY(r) ((((r) ^ ((r) >> 3)) & 7) << 3)  // GEMM LDS k-chunk swizzle key
#define VKEY(d) ((((d) >> 3) & 7) << 3)          // attn Vt k swizzle key

static __device__ __forceinline__ u16 f2b(float f) {
  union { float f; unsigned u; } x; x.f = f;
  unsigned r = x.u + 0x7FFFu + ((x.u >> 16) & 1u);  // RNE
  return (u16)(r >> 16);
}

static __device__ __forceinline__ bf16x8 ld_frag(const u16* p) {
  union { u16x8 s; bf16x8 b; } u;
  u.s = *reinterpret_cast<const u16x8*>(p);
  return u.b;
}

// ---------------- f32 -> bf16 convert (vectorized x4) ----------------
__global__ __launch_bounds__(256) void cvt_f32_bf16(const float* __restrict__ in,
                                                    u16* __restrict__ out, int n4) {
  int i = blockIdx.x * 256 + threadIdx.x;
  if (i >= n4) return;
  float4 v = reinterpret_cast<const float4*>(in)[i];
  ushort4 o;
  o.x = f2b(v.x); o.y = f2b(v.y); o.z = f2b(v.z); o.w = f2b(v.w);
  reinterpret_cast<ushort4*>(out)[i] = o;
}

// ---------------- GEMM v2: out[M,N] = (A[M,K] @ Bt[N,K]^T + bias) * scale ----
// 128x64 tile, BK=64, 4 waves (2x2), global_load_lds w16 with pre-swizzled
// source (linear LDS dest, XOR-swizzled ds_read) per rule #21.
__global__ __launch_bounds__(256) void gemm_bt2(
    const u16* __restrict__ A, const u16* __restrict__ Bt,
    const float* __restrict__ bias, void* __restrict__ outp,
    int M, int N, int K, float scale, int out_bf16) {
  __shared__ alignas(16) u16 As[128 * 64];
  __shared__ alignas(16) u16 Bs[64 * 64];
  const int tid = threadIdx.x, wid = tid >> 6, lane = tid & 63;
  const int wr = wid >> 1, wc = wid & 1;
  const int row0 = blockIdx.x * 128, col0 = blockIdx.y * 64;
  const int lr = lane >> 3;         // 0..7 (row within an 8-row issue)
  const int lc = (lane & 7) * 8;    // k-chunk 0..56
  const int frow = lane & 15, fk = (lane >> 4) * 8;
  f32x4 acc[4][2] = {};

  for (int k0 = 0; k0 < K; k0 += 64) {
    __syncthreads();
    // stage A: wave w covers rows [32w, 32w+32), 4 issues x 8 rows
#pragma unroll
    for (int t = 0; t < 4; ++t) {
      const int r = wid * 32 + t * 8 + lr;
      __builtin_amdgcn_global_load_lds(
          (const __attribute__((address_space(1))) unsigned int*)(
              A + (size_t)(row0 + r) * K + k0 + (lc ^ KEY(r))),
          (__attribute__((address_space(3))) unsigned int*)(As + (wid * 32 + t * 8) * 64),
          16, 0, 0);
    }
    // stage B: wave w covers rows [16w, 16w+16), 2 issues
#pragma unroll
    for (int t = 0; t < 2; ++t) {
      const int r = wid * 16 + t * 8 + lr;
      __builtin_amdgcn_global_load_lds(
          (const __attribute__((address_space(1))) unsigned int*)(
              Bt + (size_t)(col0 + r) * K + k0 + (lc ^ KEY(r))),
          (__attribute__((address_space(3))) unsigned int*)(Bs + (wid * 16 + t * 8) * 64),
          16, 0, 0);
    }
    __syncthreads();
#pragma unroll
    for (int ks = 0; ks < 2; ++ks) {
      bf16x8 a[4], b[2];
#pragma unroll
      for (int m = 0; m < 4; ++m) {
        const int r = wr * 64 + m * 16 + frow;
        a[m] = ld_frag(&As[r * 64 + ((ks * 32 + fk) ^ KEY(r))]);
      }
#pragma unroll
      for (int n = 0; n < 2; ++n) {
        const int r = wc * 32 + n * 16 + frow;
        b[n] = ld_frag(&Bs[r * 64 + ((ks * 32 + fk) ^ KEY(r))]);
      }
#pragma unroll
      for (int m = 0; m < 4; ++m)
#pragma unroll
        for (int n = 0; n < 2; ++n)
          acc[m][n] = __builtin_amdgcn_mfma_f32_16x16x32_bf16(a[m], b[n], acc[m][n], 0, 0, 0);
    }
  }
  // epilogue: D layout col=lane&15, row=(lane>>4)*4+r
  const int colL = lane & 15, rb = (lane >> 4) * 4;
#pragma unroll
  for (int n = 0; n < 2; ++n) {
    const int gc = col0 + wc * 32 + n * 16 + colL;
    const float bv = bias[gc];
#pragma unroll
    for (int m = 0; m < 4; ++m)
#pragma unroll
      for (int r = 0; r < 4; ++r) {
        const int gr = row0 + wr * 64 + m * 16 + rb + r;
        const float v = (acc[m][n][r] + bv) * scale;
        if (out_bf16) reinterpret_cast<u16*>(outp)[(size_t)gr * N + gc] = f2b(v);
        else reinterpret_cast<float*>(outp)[(size_t)gr * N + gc] = v;
      }
  }
}

// ---------------- Flash attention with ALiBi + causal ----------------
// grid: (B*H, T/64) with qt = gridDim.y-1-blockIdx.y (LPT schedule).
// block: 256 (4 waves), wave w owns q rows [qBase+16w, +16).
// V staged TRANSPOSED in LDS (Vt[d][k^VKEY(d)], pitch GP) so PV B-fragments
// are ds_read_b128 like the K fragments.
__global__ __launch_bounds__(256) void attn_kernel(
    const u16* __restrict__ qb,   // [B*T, 1024] bf16, pre-scaled by 1/8
    const u16* __restrict__ kvb,  // [B*T, 2048] bf16 (k: cols h*64, v: 1024+h*64)
    u16* __restrict__ yb,         // [B*T, 1024] bf16
    int T) {
  const int C = 1024;
  const int bh = blockIdx.x;
  const int qt = gridDim.y - 1 - blockIdx.y;
  const int b = bh >> 4, h = bh & 15;
  const float slope = (float)(h + 1) * 0.0625f;  // (h+1)/16
  const int tid = threadIdx.x, wid = tid >> 6, lane = tid & 63;
  const int qBase = qt * 64;

  __shared__ alignas(16) u16 Ks[64 * GP];   // K[k][d]
  __shared__ alignas(16) u16 Vt[64 * GP];   // V^T: Vt[d][k ^ VKEY(d)]
  __shared__ alignas(16) u16 Ps[4][16 * GP];

  const int frow = lane & 15, fk = (lane >> 4) * 8;
  const int col = lane & 15, rb = (lane >> 4) * 4;

  // Q fragments (loop-invariant)
  const int q_row = qBase + wid * 16 + frow;
  const u16* qp = qb + (size_t)(b * T + q_row) * C + h * 64;
  const bf16x8 aq0 = ld_frag(qp + fk);
  const bf16x8 aq1 = ld_frag(qp + 32 + fk);

  float mrow[4] = {-1e30f, -1e30f, -1e30f, -1e30f};
  float lrow[4] = {0.f, 0.f, 0.f, 0.f};
  f32x4 accO[4] = {};

  const int sr = tid >> 3;        // 0..31
  const int sc = (tid & 7) * 8;   // 0..56

  for (int kt = 0; kt <= qt; ++kt) {
    const int kBase = kt * 64;
    __syncthreads();  // previous iteration's reads of Ks/Vt done
    {  // stage K rows + V transposed
      const size_t g0 = (size_t)(b * T + kBase + sr) * 2048 + h * 64 + sc;
      const size_t g1 = (size_t)(b * T + kBase + sr + 32) * 2048 + h * 64 + sc;
      *reinterpret_cast<int4*>(&Ks[sr * GP + sc]) = *reinterpret_cast<const int4*>(&kvb[g0]);
      *reinterpret_cast<int4*>(&Ks[(sr + 32) * GP + sc]) = *reinterpret_cast<const int4*>(&kvb[g1]);
      int4 v0 = *reinterpret_cast<const int4*>(&kvb[g0 + 1024]);
      int4 v1 = *reinterpret_cast<const int4*>(&kvb[g1 + 1024]);
      const u16* p0 = reinterpret_cast<const u16*>(&v0);
      const u16* p1 = reinterpret_cast<const u16*>(&v1);
      const int kx = VKEY(sc);  // d>>3 == sc>>3 for all 8 elems
#pragma unroll
      for (int j = 0; j < 8; ++j) {
        const int d = sc + j;
        Vt[d * GP + (sr ^ kx)] = p0[j];
        Vt[d * GP + ((sr + 32) ^ kx)] = p1[j];
      }
    }
    __syncthreads();

    // S = Q K^T (per wave: 16 q-rows x 64 keys)
    f32x4 accS[4] = {};
#pragma unroll
    for (int n = 0; n < 4; ++n) {
      bf16x8 bk0 = ld_frag(&Ks[(n * 16 + frow) * GP + fk]);
      accS[n] = __builtin_amdgcn_mfma_f32_16x16x32_bf16(aq0, bk0, accS[n], 0, 0, 0);
      bf16x8 bk1 = ld_frag(&Ks[(n * 16 + frow) * GP + 32 + fk]);
      accS[n] = __builtin_amdgcn_mfma_f32_16x16x32_bf16(aq1, bk1, accS[n], 0, 0, 0);
    }

    // online softmax per owned row r (rows replicated across each 16-lane group)
#pragma unroll
    for (int r = 0; r < 4; ++r) {
      const int qg = qBase + wid * 16 + rb + r;
      float s[4];
      float tmax = -1e30f;
#pragma unroll
      for (int n = 0; n < 4; ++n) {
        const int kg = kBase + n * 16 + col;
        float v = accS[n][r] + slope * (float)(kg - qg);
        if (kg > qg) v = -1e30f;
        s[n] = v;
        tmax = fmaxf(tmax, v);
      }
      tmax = fmaxf(tmax, __shfl_xor(tmax, 1));
      tmax = fmaxf(tmax, __shfl_xor(tmax, 2));
      tmax = fmaxf(tmax, __shfl_xor(tmax, 4));
      tmax = fmaxf(tmax, __shfl_xor(tmax, 8));
      const float newm = fmaxf(mrow[r], tmax);
      const float corr = __expf(mrow[r] - newm);
      mrow[r] = newm;
      float psum = 0.f;
#pragma unroll
      for (int n = 0; n < 4; ++n) {
        const float p = __expf(s[n] - newm);
        psum += p;
        Ps[wid][(rb + r) * GP + n * 16 + col] = f2b(p);
      }
      psum += __shfl_xor(psum, 1);
      psum += __shfl_xor(psum, 2);
      psum += __shfl_xor(psum, 4);
      psum += __shfl_xor(psum, 8);
      lrow[r] = lrow[r] * corr + psum;
#pragma unroll
      for (int n = 0; n < 4; ++n) accO[n][r] *= corr;
    }
    // no barrier: Ps is per-wave; within-wave ds_write->ds_read is ordered

    // O += P @ V   (B-fragment = V^T rows, vectorized b128 from Vt)
#pragma unroll
    for (int ks = 0; ks < 2; ++ks) {
      bf16x8 ap = ld_frag(&Ps[wid][frow * GP + ks * 32 + fk]);
#pragma unroll
      for (int n = 0; n < 4; ++n) {
        const int d = n * 16 + frow;
        bf16x8 bv = ld_frag(&Vt[d * GP + ((ks * 32 + fk) ^ VKEY(d))]);
        accO[n] = __builtin_amdgcn_mfma_f32_16x16x32_bf16(ap, bv, accO[n], 0, 0, 0);
      }
    }
  }

  // normalize + store
#pragma unroll
  for (int r = 0; r < 4; ++r) {
    const float inv = 1.0f / lrow[r];
    const int qg = qBase + wid * 16 + rb + r;
    u16* yrow = yb + (size_t)(b * T + qg) * C + h * 64;
#pragma unroll
    for (int n = 0; n < 4; ++n) yrow[n * 16 + col] = f2b(accO[n][r] * inv);
  }
}

extern "C" void kernel_launch(void* const* d_in, const int* in_sizes, int n_in,
                              void* d_out, int out_size, void* d_ws, size_t ws_size,
                              hipStream_t stream) {
  const float* x   = (const float*)d_in[0];
  // d_in[1] = freqs_cis (unused under ALiBi)
  const float* Wq  = (const float*)d_in[2];
  const float* bq  = (const float*)d_in[3];
  const float* Wkv = (const float*)d_in[4];
  const float* bkv = (const float*)d_in[5];
  const float* Wo  = (const float*)d_in[6];
  const float* bo  = (const float*)d_in[7];
  float* out = (float*)d_out;

  const int B = 2, T = 2048, C = 1024;
  const int M = B * T;  // 4096

  char* ws = (char*)d_ws;
  u16* xb   = (u16*)(ws + 0);          // 4096x1024  (8 MiB)
  u16* wqb  = (u16*)(ws + 8388608);    // 1024x1024  (2 MiB)
  u16* wkvb = (u16*)(ws + 10485760);   // 2048x1024  (4 MiB)
  u16* wob  = (u16*)(ws + 14680064);   // 1024x1024  (2 MiB)
  u16* qb   = (u16*)(ws + 16777216);   // 4096x1024  (8 MiB)
  u16* kvb  = (u16*)(ws + 25165824);   // 4096x2048  (16 MiB)
  u16* yb   = (u16*)(ws + 41943040);   // 4096x1024  (8 MiB)

  cvt_f32_bf16<<<(M * C / 4 + 255) / 256, 256, 0, stream>>>(x, xb, M * C / 4);
  cvt_f32_bf16<<<(C * C / 4 + 255) / 256, 256, 0, stream>>>(Wq, wqb, C * C / 4);
  cvt_f32_bf16<<<(2 * C * C / 4 + 255) / 256, 256, 0, stream>>>(Wkv, wkvb, 2 * C * C / 4);
  cvt_f32_bf16<<<(C * C / 4 + 255) / 256, 256, 0, stream>>>(Wo, wob, C * C / 4);

  // q = (x @ Wq^T + bq) * 0.125   [fold 1/sqrt(64) into q]
  gemm_bt2<<<dim3(M / 128, C / 64), 256, 0, stream>>>(xb, wqb, bq, qb, M, C, C, 0.125f, 1);
  // kv = x @ Wkv^T + bkv
  gemm_bt2<<<dim3(M / 128, 2 * C / 64), 256, 0, stream>>>(xb, wkvb, bkv, kvb, M, 2 * C, C, 1.0f, 1);
  // flash attention (grid: bh x qtile, reversed for LPT balance)
  attn_kernel<<<dim3(B * 16, T / 64), 256, 0, stream>>>(qb, kvb, yb, T);
  // out = y @ Wo^T + bo  (f32 out)
  gemm_bt2<<<dim3(M / 128, C / 64), 256, 0, stream>>>(yb, wob, bo, out, M, C, C, 1.0f, 0);
}